// Round 3
// baseline (6288.206 us; speedup 1.0000x reference)
//
#include <hip/hip_runtime.h>

typedef unsigned short u16;
typedef __attribute__((ext_vector_type(8))) short s8v;

#define L_DIM 1024
#define N_DIM 16384
#define R_DIM 128
#define PEN  -10000.0f

__device__ __forceinline__ float b2f(u16 x) { return __uint_as_float(((unsigned)x) << 16); }
__device__ __forceinline__ u16 f2bf(float f) {
    unsigned u = __float_as_uint(f);
    unsigned r = (u + 0x7FFFu + ((u >> 16) & 1u)) >> 16;
    return (u16)r;
}
// monotone float<->uint map for atomicMax on floats; 0u is below every mapped float
__device__ __forceinline__ unsigned fmapu(float f) {
    unsigned u = __float_as_uint(f);
    return (u & 0x80000000u) ? ~u : (u | 0x80000000u);
}
__device__ __forceinline__ float funmap(unsigned u) {
    unsigned b = (u & 0x80000000u) ? (u & 0x7fffffffu) : ~u;
    return __uint_as_float(b);
}
// flag=0: 4-byte elements (int32 OR float32 bools — nonzero word test covers both)
// flag=1: 1-byte elements
__device__ __forceinline__ int mask_ok(const void* al, int fl, size_t idx) {
    if (fl) return ((const unsigned char*)al)[idx] != 0;
    return ((const unsigned*)al)[idx] != 0u;
}

__device__ __forceinline__ float blk_max(float x, float* scr) {
#pragma unroll
    for (int o = 32; o > 0; o >>= 1) x = fmaxf(x, __shfl_xor(x, o));
    __syncthreads();
    if ((threadIdx.x & 63) == 0) scr[threadIdx.x >> 6] = x;
    __syncthreads();
    return fmaxf(fmaxf(scr[0], scr[1]), fmaxf(scr[2], scr[3]));
}
__device__ __forceinline__ float blk_sum(float x, float* scr) {
#pragma unroll
    for (int o = 32; o > 0; o >>= 1) x += __shfl_xor(x, o);
    __syncthreads();
    if ((threadIdx.x & 63) == 0) scr[threadIdx.x >> 6] = x;
    __syncthreads();
    return scr[0] + scr[1] + scr[2] + scr[3];
}

// -------- detect allowed element width --------------------------------------
__global__ void detect_k(const unsigned* __restrict__ a, int* __restrict__ flag) {
    int bad = 0;
    for (int i = threadIdx.x; i < 4096; i += 256) {
        unsigned w = a[i];
        if (w != 0u && w != 1u && w != 0x3F800000u) bad = 1;
    }
    if (bad) *flag = 1;
}

// -------- per-row top-128 (radix select) + log_softmax over the set ---------
__global__ __launch_bounds__(256) void topk_lsm_k(const float* __restrict__ U,
                                                  int* __restrict__ candg,
                                                  float* __restrict__ lsmg) {
    const int t = blockIdx.x;
    const float* row = U + (size_t)t * N_DIM;
    __shared__ unsigned hist[256];
    __shared__ int sel[2];
    __shared__ int cnts[2];
    __shared__ float vals[128];
    __shared__ int inds[128];
    __shared__ float scr[4];
    const int tid = threadIdx.x;
    unsigned prefix = 0;
    int kneed = 128;
    for (int pass = 0; pass < 4; ++pass) {
        const int sh = 24 - pass * 8;
        hist[tid] = 0;
        __syncthreads();
        for (int i = tid; i < N_DIM; i += 256) {
            unsigned u = __float_as_uint(row[i]);
            unsigned k = (u & 0x80000000u) ? ~u : (u | 0x80000000u);
            bool match = (pass == 0) || ((k >> (sh + 8)) == prefix);
            if (match) atomicAdd(&hist[(k >> sh) & 255u], 1u);
        }
        __syncthreads();
        if (tid == 0) {
            int acc = 0, d = 0;
            for (int dig = 255; dig >= 0; --dig) {
                int c = (int)hist[dig];
                if (acc + c >= kneed) { d = dig; break; }
                acc += c;
            }
            sel[0] = d; sel[1] = acc;
        }
        __syncthreads();
        kneed -= sel[1];
        prefix = (prefix << 8) | (unsigned)sel[0];
        __syncthreads();
    }
    const unsigned K = prefix;
    if (tid < 2) cnts[tid] = 0;
    if (tid < 128) { vals[tid] = -1.0e30f; inds[tid] = 0; }
    __syncthreads();
    for (int i = tid; i < N_DIM; i += 256) {
        float f = row[i];
        unsigned u = __float_as_uint(f);
        unsigned k = (u & 0x80000000u) ? ~u : (u | 0x80000000u);
        if (k > K) { int p = atomicAdd(&cnts[0], 1); if (p < 128) { vals[p] = f; inds[p] = i; } }
    }
    __syncthreads();
    const int cgt = min(cnts[0], 128);
    for (int i = tid; i < N_DIM; i += 256) {
        float f = row[i];
        unsigned u = __float_as_uint(f);
        unsigned k = (u & 0x80000000u) ? ~u : (u | 0x80000000u);
        if (k == K) {
            int p = atomicAdd(&cnts[1], 1);
            if (cgt + p < 128) { vals[cgt + p] = f; inds[cgt + p] = i; }
        }
    }
    __syncthreads();
    float xv = (tid < 128) ? vals[tid] : -3.0e38f;
    float mx = blk_max(xv, scr);
    float ex = (tid < 128) ? __expf(vals[tid] - mx) : 0.f;
    float sm = blk_sum(ex, scr);
    float lse = mx + __logf(fmaxf(sm, 1e-37f));
    if (tid < 128) {
        candg[t * 128 + tid] = min(max(inds[tid], 0), N_DIM - 1);
        lsmg[t * 128 + tid] = vals[tid] - lse;
    }
}

// -------- cast H to bf16 ----------------------------------------------------
__global__ void cast_h_k(const float* __restrict__ H, u16* __restrict__ Hbf) {
    size_t base = ((size_t)blockIdx.x * 256 + threadIdx.x) * 4;
    float4 f = *(const float4*)(H + base);
    ushort4 o;
    o.x = f2bf(f.x); o.y = f2bf(f.y); o.z = f2bf(f.z); o.w = f2bf(f.w);
    *(ushort4*)(Hbf + base) = o;
}

// -------- HW = H @ W (fp32 VALU, bf16 out); 8 rows per block ----------------
__global__ __launch_bounds__(256) void gemm_hw_k(const float* __restrict__ H,
                                                 const float* __restrict__ W,
                                                 u16* __restrict__ HWbf) {
    const int r0 = blockIdx.x * 8;
    __shared__ float Hl[8][512];
    for (int idx = threadIdx.x; idx < 8 * 512; idx += 256) {
        int r = idx >> 9, k = idx & 511;
        Hl[r][k] = H[(size_t)(r0 + r) * 512 + k];
    }
    __syncthreads();
    const int c = threadIdx.x;
    float acc0[8], acc1[8];
#pragma unroll
    for (int r = 0; r < 8; ++r) { acc0[r] = 0.f; acc1[r] = 0.f; }
    for (int k = 0; k < 512; ++k) {
        float w0 = W[(size_t)k * 512 + c];
        float w1 = W[(size_t)k * 512 + c + 256];
#pragma unroll
        for (int r = 0; r < 8; ++r) {
            float h = Hl[r][k];
            acc0[r] += h * w0;
            acc1[r] += h * w1;
        }
    }
#pragma unroll
    for (int r = 0; r < 8; ++r) {
        HWbf[(size_t)(r0 + r) * 512 + c] = f2bf(acc0[r]);
        HWbf[(size_t)(r0 + r) * 512 + c + 256] = f2bf(acc1[r]);
    }
}

// -------- per-step pair matrix -> (E row-major bf16, c fp32), pure VALU -----
__global__ __launch_bounds__(256) void pair_k(const int* __restrict__ candg,
                                              const float* __restrict__ lsmg,
                                              const u16* __restrict__ HWbf,
                                              const u16* __restrict__ Hbf,
                                              const void* __restrict__ allowed,
                                              const int* __restrict__ flag,
                                              u16* __restrict__ Eg,
                                              float* __restrict__ cvec) {
    const int t = blockIdx.x + 1;
    __shared__ u16 Hl[32][520];
    __shared__ int sprev[128], scur[128];
    __shared__ unsigned scm[32];
    __shared__ float scmf[32];
    const int tid = threadIdx.x;
    if (tid < 128) {
        sprev[tid] = min(max(candg[(t - 1) * 128 + tid], 0), N_DIM - 1);
        scur[tid]  = min(max(candg[t * 128 + tid], 0), N_DIM - 1);
    }
    __syncthreads();
    const int fl = *flag;
    const int i = tid >> 1;               // prev row 0..127
    const int jh = tid & 1;               // 16-column half of a 32-col pass
    const size_t prow = (size_t)sprev[i] * 512;
    u16* Eo = Eg + (size_t)(t - 1) * 16384;
    for (int p = 0; p < 4; ++p) {
        for (int idx = tid; idx < 32 * 64; idx += 256) {
            int r = idx >> 6, v = idx & 63;
            *(s8v*)&Hl[r][v * 8] = *(const s8v*)(Hbf + (size_t)scur[p * 32 + r] * 512 + v * 8);
        }
        if (tid < 32) scm[tid] = 0u;
        __syncthreads();
        float acc[16];
#pragma unroll
        for (int jj = 0; jj < 16; ++jj) acc[jj] = 0.f;
        for (int k8 = 0; k8 < 64; ++k8) {
            s8v hv = *(const s8v*)(HWbf + prow + k8 * 8);
            float a[8];
#pragma unroll
            for (int e = 0; e < 8; ++e) a[e] = b2f((u16)hv[e]);
#pragma unroll
            for (int jj = 0; jj < 16; ++jj) {
                s8v hl = *(const s8v*)&Hl[jh * 16 + jj][k8 * 8];
#pragma unroll
                for (int e = 0; e < 8; ++e) acc[jj] += a[e] * b2f((u16)hl[e]);
            }
        }
#pragma unroll
        for (int jj = 0; jj < 16; ++jj) {
            int jl = jh * 16 + jj;
            int j = p * 32 + jl;
            if (!mask_ok(allowed, fl, (size_t)scur[j] * N_DIM + (size_t)sprev[i])) acc[jj] += PEN;
            atomicMax(&scm[jl], fmapu(acc[jj]));
        }
        __syncthreads();
        if (tid < 32) {
            float cm = funmap(scm[tid]);
            scmf[tid] = cm;
            cvec[(size_t)(t - 1) * 128 + p * 32 + tid] = cm + lsmg[(size_t)t * 128 + p * 32 + tid];
        }
        __syncthreads();
#pragma unroll
        for (int jj = 0; jj < 16; ++jj) {
            int jl = jh * 16 + jj;
            float e = __expf(acc[jj] - scmf[jl]);      // arg <= 0 by construction
            e = fminf(fmaxf(e, 0.f), 1.0f);            // scrub any NaN/overshoot
            Eo[(size_t)i * 128 + p * 32 + jl] = f2bf(e);
        }
        __syncthreads();
    }
}

// -------- gold path scores --------------------------------------------------
__global__ __launch_bounds__(256) void score_k(const float* __restrict__ U,
                                               const int* __restrict__ gold,
                                               const void* __restrict__ allowed,
                                               const int* __restrict__ flag,
                                               const u16* __restrict__ HWbf,
                                               const u16* __restrict__ Hbf,
                                               float* __restrict__ accums) {
    const int t = blockIdx.x;
    __shared__ float scr[4];
    float part = 0.f;
    int gp = 0, gc = 0;
    if (t < L_DIM - 1) {
        gp = min(max(gold[t], 0), N_DIM - 1);
        gc = min(max(gold[t + 1], 0), N_DIM - 1);
        const u16* ar = HWbf + (size_t)gp * 512;
        const u16* br = Hbf + (size_t)gc * 512;
        for (int k = threadIdx.x; k < 512; k += 256)
            part += b2f(ar[k]) * b2f(br[k]);
    }
    float tot = blk_sum(part, scr);
    if (threadIdx.x == 0) {
        if (t < L_DIM - 1) {
            int ok = mask_ok(allowed, *flag, (size_t)gc * N_DIM + (size_t)gp);
            atomicAdd(&accums[1], ok ? tot : PEN);
        }
        int g0 = min(max(gold[t], 0), N_DIM - 1);
        atomicAdd(&accums[0], U[(size_t)t * N_DIM + g0]);
    }
}

// -------- fully sequential scan over all 1023 (E,c) factors ----------------
// alpha'[k] = log( sum_i exp(alpha[i]-vmax) * E[i][k] ) + vmax + c[k]
// No divisions, no renormalization: numerically isomorphic to the reference.
__global__ __launch_bounds__(256) void seq_final_k(const u16* __restrict__ Eg,
                                                   const float* __restrict__ cvec,
                                                   const float* __restrict__ lsmg,
                                                   const float* __restrict__ accums,
                                                   float* __restrict__ out) {
    __shared__ float v[128], p[128];
    __shared__ u16 Et[16384];
    __shared__ float scr[4];
    const int tid = threadIdx.x;
    if (tid < 128) v[tid] = lsmg[tid];   // alpha0 = log_softmax(u[0][cand0])
    __syncthreads();
    for (int s = 0; s < L_DIM - 1; ++s) {
        const u16* Es = Eg + (size_t)s * 16384;
        for (int idx = tid; idx < 2048; idx += 256)
            *(s8v*)&Et[idx * 8] = *(const s8v*)(Es + idx * 8);
        float x = (tid < 128) ? v[tid] : -3.0e38f;
        float vmax = blk_max(x, scr);
        if (tid < 128) p[tid] = __expf(v[tid] - vmax);
        __syncthreads();   // Et + p visible
        float nv = 0.f;
        if (tid < 128) {
            float a = 0.f;
            for (int i = 0; i < 128; ++i) a += p[i] * b2f(Et[i * 128 + tid]);
            nv = ((a > 1e-30f) ? __logf(a) : -1.0e30f) + vmax + cvec[(size_t)s * 128 + tid];
        }
        __syncthreads();   // all Et reads done before next-iter overwrite
        if (tid < 128) v[tid] = nv;
        __syncthreads();
    }
    float x = (tid < 128) ? v[tid] : -3.0e38f;
    float mz = blk_max(x, scr);
    float e = (tid < 128) ? __expf(v[tid] - mz) : 0.f;
    float sm = blk_sum(e, scr);
    if (tid == 0) out[0] = mz + __logf(fmaxf(sm, 1e-37f)) - (accums[0] + accums[1]);
}

extern "C" void kernel_launch(void* const* d_in, const int* in_sizes, int n_in,
                              void* d_out, int out_size, void* d_ws, size_t ws_size,
                              hipStream_t stream) {
    const float* U = (const float*)d_in[0];
    const float* H = (const float*)d_in[1];
    const float* W = (const float*)d_in[2];
    const int* gold = (const int*)d_in[3];
    const void* allowed = (const void*)d_in[4];

    char* ws = (char*)d_ws;
    float* accums = (float*)ws;            // [0]=score_unary, [1]=score_pair
    int* flag = (int*)(ws + 8);
    size_t off = 256;
    int* cand = (int*)(ws + off);     off += (size_t)L_DIM * R_DIM * 4;
    float* lsm = (float*)(ws + off);  off += (size_t)L_DIM * R_DIM * 4;
    u16* Hbf = (u16*)(ws + off);      off += (size_t)N_DIM * 512 * 2;
    u16* HWbf = (u16*)(ws + off);     off += (size_t)N_DIM * 512 * 2;
    u16* E = (u16*)(ws + off);        off += (size_t)(L_DIM - 1) * 16384 * 2;
    float* cvec = (float*)(ws + off); off += (size_t)(L_DIM - 1) * 128 * 4;

    hipMemsetAsync(d_ws, 0, 256, stream);
    detect_k<<<1, 256, 0, stream>>>((const unsigned*)d_in[4], flag);
    topk_lsm_k<<<L_DIM, 256, 0, stream>>>(U, cand, lsm);
    cast_h_k<<<(N_DIM * 512) / (256 * 4), 256, 0, stream>>>(H, Hbf);
    gemm_hw_k<<<N_DIM / 8, 256, 0, stream>>>(H, W, HWbf);
    pair_k<<<L_DIM - 1, 256, 0, stream>>>(cand, lsm, HWbf, Hbf, allowed, flag, E, cvec);
    score_k<<<L_DIM, 256, 0, stream>>>(U, gold, allowed, flag, HWbf, Hbf, accums);
    seq_final_k<<<1, 256, 0, stream>>>(E, cvec, lsm, accums, (float*)d_out);
}

// Round 5
// 3576.086 us; speedup vs baseline: 1.7584x; 1.7584x over previous
//
#include <hip/hip_runtime.h>

typedef unsigned short u16;
typedef __attribute__((ext_vector_type(8))) short s8v;

#define L_DIM 1024
#define N_DIM 16384
#define R_DIM 128
#define PEN  -10000.0f

__device__ __forceinline__ float b2f(u16 x) { return __uint_as_float(((unsigned)x) << 16); }
__device__ __forceinline__ u16 f2bf(float f) {
    unsigned u = __float_as_uint(f);
    unsigned r = (u + 0x7FFFu + ((u >> 16) & 1u)) >> 16;
    return (u16)r;
}
__device__ __forceinline__ unsigned fmapu(float f) {
    unsigned u = __float_as_uint(f);
    return (u & 0x80000000u) ? ~u : (u | 0x80000000u);
}
__device__ __forceinline__ float funmap(unsigned u) {
    unsigned b = (u & 0x80000000u) ? (u & 0x7fffffffu) : ~u;
    return __uint_as_float(b);
}
// flag=0: 4-byte elements (int32 OR float32 bools); flag=1: 1-byte elements
__device__ __forceinline__ int mask_ok(const void* al, int fl, size_t idx) {
    if (fl) return ((const unsigned char*)al)[idx] != 0;
    return ((const unsigned*)al)[idx] != 0u;
}

__device__ __forceinline__ float blk_max(float x, float* scr) {
#pragma unroll
    for (int o = 32; o > 0; o >>= 1) x = fmaxf(x, __shfl_xor(x, o));
    __syncthreads();
    if ((threadIdx.x & 63) == 0) scr[threadIdx.x >> 6] = x;
    __syncthreads();
    return fmaxf(fmaxf(scr[0], scr[1]), fmaxf(scr[2], scr[3]));
}
__device__ __forceinline__ float blk_sum(float x, float* scr) {
#pragma unroll
    for (int o = 32; o > 0; o >>= 1) x += __shfl_xor(x, o);
    __syncthreads();
    if ((threadIdx.x & 63) == 0) scr[threadIdx.x >> 6] = x;
    __syncthreads();
    return scr[0] + scr[1] + scr[2] + scr[3];
}

// -------- detect allowed element width --------------------------------------
__global__ void detect_k(const unsigned* __restrict__ a, int* __restrict__ flag) {
    int bad = 0;
    for (int i = threadIdx.x; i < 4096; i += 256) {
        unsigned w = a[i];
        if (w != 0u && w != 1u && w != 0x3F800000u) bad = 1;
    }
    if (bad) *flag = 1;
}

// -------- per-row top-128 (radix select) + log_softmax over the set ---------
__global__ __launch_bounds__(256) void topk_lsm_k(const float* __restrict__ U,
                                                  int* __restrict__ candg,
                                                  float* __restrict__ lsmg) {
    const int t = blockIdx.x;
    const float* row = U + (size_t)t * N_DIM;
    __shared__ unsigned hist[256];
    __shared__ int sel[2];
    __shared__ int cnts[2];
    __shared__ float vals[128];
    __shared__ int inds[128];
    __shared__ float scr[4];
    const int tid = threadIdx.x;
    unsigned prefix = 0;
    int kneed = 128;
    for (int pass = 0; pass < 4; ++pass) {
        const int sh = 24 - pass * 8;
        hist[tid] = 0;
        __syncthreads();
        for (int i = tid; i < N_DIM; i += 256) {
            unsigned u = __float_as_uint(row[i]);
            unsigned k = (u & 0x80000000u) ? ~u : (u | 0x80000000u);
            bool match = (pass == 0) || ((k >> (sh + 8)) == prefix);
            if (match) atomicAdd(&hist[(k >> sh) & 255u], 1u);
        }
        __syncthreads();
        if (tid == 0) {
            int acc = 0, d = 0;
            for (int dig = 255; dig >= 0; --dig) {
                int c = (int)hist[dig];
                if (acc + c >= kneed) { d = dig; break; }
                acc += c;
            }
            sel[0] = d; sel[1] = acc;
        }
        __syncthreads();
        kneed -= sel[1];
        prefix = (prefix << 8) | (unsigned)sel[0];
        __syncthreads();
    }
    const unsigned K = prefix;
    if (tid < 2) cnts[tid] = 0;
    if (tid < 128) { vals[tid] = -1.0e30f; inds[tid] = 0; }
    __syncthreads();
    for (int i = tid; i < N_DIM; i += 256) {
        float f = row[i];
        unsigned u = __float_as_uint(f);
        unsigned k = (u & 0x80000000u) ? ~u : (u | 0x80000000u);
        if (k > K) { int p = atomicAdd(&cnts[0], 1); if (p < 128) { vals[p] = f; inds[p] = i; } }
    }
    __syncthreads();
    const int cgt = min(cnts[0], 128);
    for (int i = tid; i < N_DIM; i += 256) {
        float f = row[i];
        unsigned u = __float_as_uint(f);
        unsigned k = (u & 0x80000000u) ? ~u : (u | 0x80000000u);
        if (k == K) {
            int p = atomicAdd(&cnts[1], 1);
            if (cgt + p < 128) { vals[cgt + p] = f; inds[cgt + p] = i; }
        }
    }
    __syncthreads();
    float xv = (tid < 128) ? vals[tid] : -3.0e38f;
    float mx = blk_max(xv, scr);
    float ex = (tid < 128) ? __expf(vals[tid] - mx) : 0.f;
    float sm = blk_sum(ex, scr);
    float lse = mx + __logf(fmaxf(sm, 1e-37f));
    if (tid < 128) {
        candg[t * 128 + tid] = min(max(inds[tid], 0), N_DIM - 1);
        lsmg[t * 128 + tid] = vals[tid] - lse;
    }
}

// -------- cast H to bf16 ----------------------------------------------------
__global__ void cast_h_k(const float* __restrict__ H, u16* __restrict__ Hbf) {
    size_t base = ((size_t)blockIdx.x * 256 + threadIdx.x) * 4;
    float4 f = *(const float4*)(H + base);
    ushort4 o;
    o.x = f2bf(f.x); o.y = f2bf(f.y); o.z = f2bf(f.z); o.w = f2bf(f.w);
    *(ushort4*)(Hbf + base) = o;
}

// -------- HW = H @ W (fp32 VALU, bf16 out); 8 rows per block ----------------
__global__ __launch_bounds__(256) void gemm_hw_k(const float* __restrict__ H,
                                                 const float* __restrict__ W,
                                                 u16* __restrict__ HWbf) {
    const int r0 = blockIdx.x * 8;
    __shared__ float Hl[8][512];
    for (int idx = threadIdx.x; idx < 8 * 512; idx += 256) {
        int r = idx >> 9, k = idx & 511;
        Hl[r][k] = H[(size_t)(r0 + r) * 512 + k];
    }
    __syncthreads();
    const int c = threadIdx.x;
    float acc0[8], acc1[8];
#pragma unroll
    for (int r = 0; r < 8; ++r) { acc0[r] = 0.f; acc1[r] = 0.f; }
    for (int k = 0; k < 512; ++k) {
        float w0 = W[(size_t)k * 512 + c];
        float w1 = W[(size_t)k * 512 + c + 256];
#pragma unroll
        for (int r = 0; r < 8; ++r) {
            float h = Hl[r][k];
            acc0[r] += h * w0;
            acc1[r] += h * w1;
        }
    }
#pragma unroll
    for (int r = 0; r < 8; ++r) {
        HWbf[(size_t)(r0 + r) * 512 + c] = f2bf(acc0[r]);
        HWbf[(size_t)(r0 + r) * 512 + c + 256] = f2bf(acc1[r]);
    }
}

// -------- per-step pair matrix -> (E row-major bf16, c fp32), pure VALU -----
__global__ __launch_bounds__(256) void pair_k(const int* __restrict__ candg,
                                              const float* __restrict__ lsmg,
                                              const u16* __restrict__ HWbf,
                                              const u16* __restrict__ Hbf,
                                              const void* __restrict__ allowed,
                                              const int* __restrict__ flag,
                                              u16* __restrict__ Eg,
                                              float* __restrict__ cvec) {
    const int t = blockIdx.x + 1;
    __shared__ u16 Hl[32][520];
    __shared__ int sprev[128], scur[128];
    __shared__ unsigned scm[32];
    __shared__ float scmf[32];
    const int tid = threadIdx.x;
    if (tid < 128) {
        sprev[tid] = min(max(candg[(t - 1) * 128 + tid], 0), N_DIM - 1);
        scur[tid]  = min(max(candg[t * 128 + tid], 0), N_DIM - 1);
    }
    __syncthreads();
    const int fl = *flag;
    const int i = tid >> 1;               // prev row 0..127
    const int jh = tid & 1;               // 16-column half of a 32-col pass
    const size_t prow = (size_t)sprev[i] * 512;
    u16* Eo = Eg + (size_t)(t - 1) * 16384;
    for (int p = 0; p < 4; ++p) {
        for (int idx = tid; idx < 32 * 64; idx += 256) {
            int r = idx >> 6, v = idx & 63;
            *(s8v*)&Hl[r][v * 8] = *(const s8v*)(Hbf + (size_t)scur[p * 32 + r] * 512 + v * 8);
        }
        if (tid < 32) scm[tid] = 0u;
        __syncthreads();
        float acc[16];
#pragma unroll
        for (int jj = 0; jj < 16; ++jj) acc[jj] = 0.f;
        for (int k8 = 0; k8 < 64; ++k8) {
            s8v hv = *(const s8v*)(HWbf + prow + k8 * 8);
            float a[8];
#pragma unroll
            for (int e = 0; e < 8; ++e) a[e] = b2f((u16)hv[e]);
#pragma unroll
            for (int jj = 0; jj < 16; ++jj) {
                s8v hl = *(const s8v*)&Hl[jh * 16 + jj][k8 * 8];
#pragma unroll
                for (int e = 0; e < 8; ++e) acc[jj] += a[e] * b2f((u16)hl[e]);
            }
        }
#pragma unroll
        for (int jj = 0; jj < 16; ++jj) {
            int jl = jh * 16 + jj;
            int j = p * 32 + jl;
            if (!mask_ok(allowed, fl, (size_t)scur[j] * N_DIM + (size_t)sprev[i])) acc[jj] += PEN;
            atomicMax(&scm[jl], fmapu(acc[jj]));
        }
        __syncthreads();
        if (tid < 32) {
            float cm = funmap(scm[tid]);
            scmf[tid] = cm;
            cvec[(size_t)(t - 1) * 128 + p * 32 + tid] = cm + lsmg[(size_t)t * 128 + p * 32 + tid];
        }
        __syncthreads();
#pragma unroll
        for (int jj = 0; jj < 16; ++jj) {
            int jl = jh * 16 + jj;
            float e = __expf(acc[jj] - scmf[jl]);      // arg <= 0 by construction
            e = fminf(fmaxf(e, 0.f), 1.0f);            // scrub any NaN/overshoot
            Eo[(size_t)i * 128 + p * 32 + jl] = f2bf(e);
        }
        __syncthreads();
    }
}

// -------- gold path scores --------------------------------------------------
__global__ __launch_bounds__(256) void score_k(const float* __restrict__ U,
                                               const int* __restrict__ gold,
                                               const void* __restrict__ allowed,
                                               const int* __restrict__ flag,
                                               const u16* __restrict__ HWbf,
                                               const u16* __restrict__ Hbf,
                                               float* __restrict__ accums) {
    const int t = blockIdx.x;
    __shared__ float scr[4];
    float part = 0.f;
    int gp = 0, gc = 0;
    if (t < L_DIM - 1) {
        gp = min(max(gold[t], 0), N_DIM - 1);
        gc = min(max(gold[t + 1], 0), N_DIM - 1);
        const u16* ar = HWbf + (size_t)gp * 512;
        const u16* br = Hbf + (size_t)gc * 512;
        for (int k = threadIdx.x; k < 512; k += 256)
            part += b2f(ar[k]) * b2f(br[k]);
    }
    float tot = blk_sum(part, scr);
    if (threadIdx.x == 0) {
        if (t < L_DIM - 1) {
            int ok = mask_ok(allowed, *flag, (size_t)gc * N_DIM + (size_t)gp);
            atomicAdd(&accums[1], ok ? tot : PEN);
        }
        int g0 = min(max(gold[t], 0), N_DIM - 1);
        atomicAdd(&accums[0], U[(size_t)t * N_DIM + g0]);
    }
}

// -------- fast sequential scan over all 1023 (E,c) factors ------------------
// Numerics identical to the verified r3 scan (log-domain alpha, per-step
// max-subtract, a>1e-30 guard). Speed: each thread holds an 8i x 8k E
// sub-block in VGPRs, prefetched one step ahead from global (L3-warm);
// dot = 64 FMA/thread; 16-way cross-group reduce via padded LDS.
__global__ __launch_bounds__(256) void seq_final_k(const u16* __restrict__ Eg,
                                                   const float* __restrict__ cvec,
                                                   const float* __restrict__ lsmg,
                                                   const float* __restrict__ accums,
                                                   float* __restrict__ out) {
    __shared__ float partial[16][132];   // [i-group][k], padded row 132
    __shared__ float v[128], p[128];
    __shared__ float scr[4];
    const int tid = threadIdx.x;
    const int ig = tid >> 4, ks = tid & 15;   // i-group 0..15 (8 rows), k-slice 0..15 (8 cols)
    typedef __attribute__((ext_vector_type(4))) unsigned int u4v;
    u4v A[8], B[8];
    {
        const u4v* base = (const u4v*)Eg;     // tile 0
#pragma unroll
        for (int ii = 0; ii < 8; ++ii) A[ii] = base[(ig * 8 + ii) * 16 + ks];
    }
    if (tid < 128) v[tid] = lsmg[tid];        // alpha0
    __syncthreads();
    for (int s = 0; s < L_DIM - 1; ++s) {
        if (s + 1 < L_DIM - 1) {
            const u4v* base = (const u4v*)(Eg + (size_t)(s + 1) * 16384);
#pragma unroll
            for (int ii = 0; ii < 8; ++ii) B[ii] = base[(ig * 8 + ii) * 16 + ks];
        }
        float x = (tid < 128) ? v[tid] : -3.0e38f;
        float vmax = blk_max(x, scr);
        if (tid < 128) p[tid] = __expf(v[tid] - vmax);
        __syncthreads();
        float pr[8];
        *(float4*)&pr[0] = *(const float4*)&p[ig * 8];
        *(float4*)&pr[4] = *(const float4*)&p[ig * 8 + 4];
        float acc[8];
#pragma unroll
        for (int e = 0; e < 8; ++e) acc[e] = 0.f;
#pragma unroll
        for (int ii = 0; ii < 8; ++ii) {
            s8v ev = *(const s8v*)&A[ii];
            float pi = pr[ii];
#pragma unroll
            for (int e = 0; e < 8; ++e) acc[e] += pi * b2f((u16)ev[e]);
        }
#pragma unroll
        for (int e = 0; e < 8; e += 2)
            *(float2*)&partial[ig][ks * 8 + e] = make_float2(acc[e], acc[e + 1]);
        __syncthreads();
        float nv = 0.f;
        if (tid < 128) {
            float a = 0.f;
#pragma unroll
            for (int g = 0; g < 16; ++g) a += partial[g][tid];
            nv = ((a > 1e-30f) ? __logf(a) : -1.0e30f) + vmax + cvec[(size_t)s * 128 + tid];
        }
        __syncthreads();
        if (tid < 128) v[tid] = nv;
        if (s + 1 < L_DIM - 1) {
#pragma unroll
            for (int ii = 0; ii < 8; ++ii) A[ii] = B[ii];
        }
    }
    float x = (tid < 128) ? v[tid] : -3.0e38f;
    float mz = blk_max(x, scr);
    float e = (tid < 128) ? __expf(v[tid] - mz) : 0.f;
    float sm = blk_sum(e, scr);
    if (tid == 0) out[0] = mz + __logf(fmaxf(sm, 1e-37f)) - (accums[0] + accums[1]);
}

extern "C" void kernel_launch(void* const* d_in, const int* in_sizes, int n_in,
                              void* d_out, int out_size, void* d_ws, size_t ws_size,
                              hipStream_t stream) {
    const float* U = (const float*)d_in[0];
    const float* H = (const float*)d_in[1];
    const float* W = (const float*)d_in[2];
    const int* gold = (const int*)d_in[3];
    const void* allowed = (const void*)d_in[4];

    char* ws = (char*)d_ws;
    float* accums = (float*)ws;            // [0]=score_unary, [1]=score_pair
    int* flag = (int*)(ws + 8);
    size_t off = 256;
    int* cand = (int*)(ws + off);     off += (size_t)L_DIM * R_DIM * 4;
    float* lsm = (float*)(ws + off);  off += (size_t)L_DIM * R_DIM * 4;
    u16* Hbf = (u16*)(ws + off);      off += (size_t)N_DIM * 512 * 2;
    u16* HWbf = (u16*)(ws + off);     off += (size_t)N_DIM * 512 * 2;
    u16* E = (u16*)(ws + off);        off += (size_t)(L_DIM - 1) * 16384 * 2;
    float* cvec = (float*)(ws + off); off += (size_t)(L_DIM - 1) * 128 * 4;

    hipMemsetAsync(d_ws, 0, 256, stream);
    detect_k<<<1, 256, 0, stream>>>((const unsigned*)d_in[4], flag);
    topk_lsm_k<<<L_DIM, 256, 0, stream>>>(U, cand, lsm);
    cast_h_k<<<(N_DIM * 512) / (256 * 4), 256, 0, stream>>>(H, Hbf);
    gemm_hw_k<<<N_DIM / 8, 256, 0, stream>>>(H, W, HWbf);
    pair_k<<<L_DIM - 1, 256, 0, stream>>>(cand, lsm, HWbf, Hbf, allowed, flag, E, cvec);
    score_k<<<L_DIM, 256, 0, stream>>>(U, gold, allowed, flag, HWbf, Hbf, accums);
    seq_final_k<<<1, 256, 0, stream>>>(E, cvec, lsm, accums, (float*)d_out);
}